// Round 13
// baseline (133.349 us; speedup 1.0000x reference)
//
#include <hip/hip_runtime.h>

// Round 13: R12 streaming kernel with ONE change: band height 16 -> 8.
// R12 evidence: kernel is per-wave dependency-latency-bound (42us even fully
// L3-resident, VALU 42-45%, only 2 waves/SIMD from the 512-block grid).
// BH=8 doubles the grid to 1024 blocks -> 4 blocks/CU (4 waves/SIMD) of
// fully independent wave-streams to interleave. Halo cost: rows 12/8 vs
// 20/16 (+20% fetch, irrelevant at 18% of HBM peak). Numerics unchanged.

constexpr int Bn = 16, Hn = 512, Wn = 512;
constexpr int BH = 8;                       // output rows per wave
constexpr int NSTRIP = 4;                   // 128-col strips
constexpr int NBAND = Hn / BH;              // 64
constexpr int NWAVE = NSTRIP * NBAND * Bn;  // 4096
constexpr int NBLK = NWAVE / 4;             // 1024 blocks x 4 waves

__device__ __forceinline__ float u8q(float v) {
    return floorf(fminf(fmaxf(v * 255.0f, 0.0f), 255.0f));
}
__device__ __forceinline__ int reflect101(int i, int n) {
    if (i < 0) return -i;
    if (i >= n) return 2 * n - 2 - i;
    return i;
}
__device__ __forceinline__ int gray1(float r, float g, float b) {
    return (int)rintf((0.299f * r + 0.587f * g) + 0.114f * b);
}
__device__ __forceinline__ int iabs(int v) { return v < 0 ? -v : v; }
// packed gray: b0=pred c0, b1=true c0, b2=pred c1, b3=true c1
__device__ __forceinline__ unsigned packG(int gp0, int gt0, int gp1, int gt1) {
    return (unsigned)gp0 | ((unsigned)gt0 << 8) | ((unsigned)gp1 << 16) |
           ((unsigned)gt1 << 24);
}
__device__ __forceinline__ int sob1(int gl, int gr, int gu, int gd) {
    const int n = iabs(gr - gl) + iabs(gd - gu);
    const int h = n >> 1;
    return h + (n & h & 1);   // RNE(n/2)
}

__global__ __launch_bounds__(256, 4)
void csl_stream(const float* __restrict__ pred, const float* __restrict__ tru,
                int2* __restrict__ ws) {
    const int tid = threadIdx.x;
    const int lane = tid & 63;
    const int wid = blockIdx.x * 4 + (tid >> 6);
    const int strip = wid & (NSTRIP - 1);
    const int band = (wid >> 2) & (NBAND - 1);
    const int img = wid >> 8;                    // 4 strips * 64 bands = 256 waves/img
    const int bs = band * BH;
    const int x0w = strip * 128;
    const int x0 = x0w + 2 * lane;               // owned cols x0, x0+1

    const size_t chs = (size_t)Hn * Wn;
    const float* pb = pred + (size_t)img * 3 * chs;
    const float* tb = tru + (size_t)img * 3 * chs;

    // boundary cols (used by lanes 0 / 63 only)
    const bool isb = (lane == 0) || (lane == 63);
    const int bc0 = (lane == 0) ? reflect101(x0w - 2, Wn) : reflect101(x0w + 128, Wn);
    const int bc1 = (lane == 0) ? reflect101(x0w - 1, Wn) : reflect101(x0w + 129, Wn);

    float2 LA[6], LB[6];   // main load sets (pred RGB, true RGB), 2 rows in flight
    float bv[12];          // boundary dwords

    auto ldMain = [&](int gy, float2* L) {
        const int gyR = reflect101(gy, Hn);
        const float* p0 = pb + (size_t)gyR * Wn + x0;
        const float* t0 = tb + (size_t)gyR * Wn + x0;
        L[0] = *(const float2*)(p0);
        L[1] = *(const float2*)(p0 + chs);
        L[2] = *(const float2*)(p0 + 2 * chs);
        L[3] = *(const float2*)(t0);
        L[4] = *(const float2*)(t0 + chs);
        L[5] = *(const float2*)(t0 + 2 * chs);
    };
    auto ldBound = [&](int gy) {
        if (isb) {
            const size_t r0 = (size_t)reflect101(gy, Hn) * Wn;
            bv[0] = pb[r0 + bc0]; bv[1] = pb[r0 + bc0 + chs]; bv[2] = pb[r0 + bc0 + 2 * chs];
            bv[3] = tb[r0 + bc0]; bv[4] = tb[r0 + bc0 + chs]; bv[5] = tb[r0 + bc0 + 2 * chs];
            bv[6] = pb[r0 + bc1]; bv[7] = pb[r0 + bc1 + chs]; bv[8] = pb[r0 + bc1 + 2 * chs];
            bv[9] = tb[r0 + bc1]; bv[10] = tb[r0 + bc1 + chs]; bv[11] = tb[r0 + bc1 + 2 * chs];
        }
    };

    unsigned G1 = 0, G2 = 0;       // gray rows s-1, s (packed)
    unsigned Gx1 = 0, Gx2 = 0;     // boundary-col gray rolling (lanes 0/63)
    unsigned mk1 = 0, mk2 = 0;     // mask-code rows rolling
    int Pk1a = 0, Pk1b = 0, Pk2a = 0, Pk2b = 0;
    int accS = 0, accE = 0;

    ldMain(bs - 2, LA);
    ldMain(bs - 1, LB);
    ldBound(bs - 2);

    auto step = [&](int i, float2* L) {
        const int gy = bs - 2 + i;
        // ---- consume main row gy -> Gn, Pk ----
        const float pr0 = u8q(L[0].x), pg0 = u8q(L[1].x), pl0 = u8q(L[2].x);
        const float tr0 = u8q(L[3].x), tg0 = u8q(L[4].x), tl0 = u8q(L[5].x);
        const float pr1 = u8q(L[0].y), pg1 = u8q(L[1].y), pl1 = u8q(L[2].y);
        const float tr1 = u8q(L[3].y), tg1 = u8q(L[4].y), tl1 = u8q(L[5].y);
        const unsigned Gn = packG(gray1(pr0, pg0, pl0), gray1(tr0, tg0, tl0),
                                  gray1(pr1, pg1, pl1), gray1(tr1, tg1, tl1));
        const int Pkna = (int)(fabsf(pr0 - tr0) + fabsf(pg0 - tg0) + fabsf(pl0 - tl0))
                       | ((int)((pr0 + pg0) + pl0) << 10)
                       | ((int)((tr0 + tg0) + tl0) << 20);
        const int Pknb = (int)(fabsf(pr1 - tr1) + fabsf(pg1 - tg1) + fabsf(pl1 - tl1))
                       | ((int)((pr1 + pg1) + pl1) << 10)
                       | ((int)((tr1 + tg1) + tl1) << 20);
        // ---- boundary gray (lanes 0/63) ----
        unsigned Gxn = 0;
        if (isb) {
            Gxn = packG(gray1(u8q(bv[0]), u8q(bv[1]), u8q(bv[2])),
                        gray1(u8q(bv[3]), u8q(bv[4]), u8q(bv[5])),
                        gray1(u8q(bv[6]), u8q(bv[7]), u8q(bv[8])),
                        gray1(u8q(bv[9]), u8q(bv[10]), u8q(bv[11])));
        }
        unsigned mkn = 0;
        if (i >= 2) {
            // ---- sobel row s = gy-1 (rows G1, G2, Gn) ----
            const unsigned GL = (unsigned)__shfl_up((int)G2, 1, 64);
            const unsigned GR = (unsigned)__shfl_down((int)G2, 1, 64);
            const unsigned lv = (lane == 0) ? Gx2 : GL;    // col x0-1 in bytes 2,3
            const unsigned rv = (lane == 63) ? Gx2 : GR;   // col x0+2 in bytes 0,1
            const int sp0 = sob1((int)((lv >> 16) & 255), (int)((G2 >> 16) & 255),
                                 (int)(G1 & 255), (int)(Gn & 255));
            const int st0 = sob1((int)((lv >> 24) & 255), (int)((G2 >> 24) & 255),
                                 (int)((G1 >> 8) & 255), (int)((Gn >> 8) & 255));
            const int sp1 = sob1((int)(G2 & 255), (int)(rv & 255),
                                 (int)((G1 >> 16) & 255), (int)((Gn >> 16) & 255));
            const int st1 = sob1((int)((G2 >> 8) & 255), (int)((rv >> 8) & 255),
                                 (int)((G1 >> 24) & 255), (int)((Gn >> 24) & 255));
            // boundary col (lane0: x0-1, lane63: x0+2)
            const bool s0l = (lane == 0);
            const int xl_p = s0l ? (int)(Gx2 & 255)        : (int)((G2 >> 16) & 255);
            const int xl_t = s0l ? (int)((Gx2 >> 8) & 255) : (int)((G2 >> 24) & 255);
            const int xr_p = s0l ? (int)(G2 & 255)         : (int)((Gx2 >> 16) & 255);
            const int xr_t = s0l ? (int)((G2 >> 8) & 255)  : (int)((Gx2 >> 24) & 255);
            const int xu_p = s0l ? (int)((Gx1 >> 16) & 255) : (int)(Gx1 & 255);
            const int xu_t = s0l ? (int)((Gx1 >> 24) & 255) : (int)((Gx1 >> 8) & 255);
            const int xd_p = s0l ? (int)((Gxn >> 16) & 255) : (int)(Gxn & 255);
            const int xd_t = s0l ? (int)((Gxn >> 24) & 255) : (int)((Gxn >> 8) & 255);
            const int spx = sob1(xl_p, xr_p, xu_p, xd_p);
            const int stx = sob1(xl_t, xr_t, xu_t, xd_t);
            mkn = (unsigned)((sp0 > 10 ? 1 : 0) | (st0 > 10 ? 2 : 0)
                  | ((sp1 > 10 ? 1 : 0) | (st1 > 10 ? 2 : 0)) << 2
                  | ((spx > 10 ? 1 : 0) | (stx > 10 ? 2 : 0)) << 4);
            if (i >= 3 && i <= BH + 2) accS += iabs(sp0 - st0) + iabs(sp1 - st1);
            if (i >= 4) {
                // ---- output row o = gy-2: blur>0 == OR over 3x3 codes ----
                const unsigned VO = mk1 | mk2 | mkn;
                const unsigned VOL = (unsigned)__shfl_up((int)VO, 1, 64);
                const unsigned VOR = (unsigned)__shfl_down((int)VO, 1, 64);
                const unsigned vl = (lane == 0) ? (VO >> 4) : (VOL >> 2);
                const unsigned vr = (lane == 63) ? (VO >> 4) : VOR;
                const unsigned k0 = (VO | vl | (VO >> 2)) & 3u;
                const unsigned k1 = ((VO >> 2) | VO | vr) & 3u;
                {
                    const int D = Pk1a & 1023, Su = (Pk1a >> 10) & 1023, St = Pk1a >> 20;
                    accE += (k0 & 1u) ? ((k0 & 2u) ? D : Su) : ((k0 & 2u) ? St : 0);
                }
                {
                    const int D = Pk1b & 1023, Su = (Pk1b >> 10) & 1023, St = Pk1b >> 20;
                    accE += (k1 & 1u) ? ((k1 & 2u) ? D : Su) : ((k1 & 2u) ? St : 0);
                }
            }
        }
        // ---- rotate pipeline ----
        G1 = G2; G2 = Gn;
        Gx1 = Gx2; Gx2 = Gxn;
        mk1 = mk2; mk2 = mkn;
        Pk1a = Pk2a; Pk1b = Pk2b; Pk2a = Pkna; Pk2b = Pknb;
        // ---- prefetch ----
        if (i < BH + 2) ldMain(gy + 2, L);
        if (i < BH + 3) ldBound(gy + 1);
    };

    for (int i = 0; i < 2 + BH + 2; i += 2) {   // 12 iterations (BH=8)
        step(i, LA);
        step(i + 1, LB);
    }

    // ---- wave reduce -> per-block int2 ----
    #pragma unroll
    for (int off = 32; off > 0; off >>= 1) {
        accS += __shfl_down(accS, off, 64);
        accE += __shfl_down(accE, off, 64);
    }
    __shared__ int wss[4], wse[4];
    const int wv = tid >> 6;
    if (lane == 0) { wss[wv] = accS; wse[wv] = accE; }
    __syncthreads();
    if (tid == 0) {
        ws[blockIdx.x] = make_int2((wss[0] + wss[1]) + (wss[2] + wss[3]),
                                   (wse[0] + wse[1]) + (wse[2] + wse[3]));
    }
}

__global__ __launch_bounds__(256)
void reduce_kernel(const int2* __restrict__ ws, float* __restrict__ out) {
    const int tid = threadIdx.x;
    int s = 0, e = 0;
    for (int i = tid; i < NBLK; i += 256) {
        const int2 v = ws[i];
        s += v.x; e += v.y;
    }
    double ds = (double)s, de = (double)e;
    #pragma unroll
    for (int off = 32; off > 0; off >>= 1) {
        ds += __shfl_down(ds, off, 64);
        de += __shfl_down(de, off, 64);
    }
    __shared__ double rs[4], re[4];
    const int wave = tid >> 6, lane = tid & 63;
    if (lane == 0) { rs[wave] = ds; re[wave] = de; }
    __syncthreads();
    if (tid == 0) {
        const double ts = (rs[0] + rs[1]) + (rs[2] + rs[3]);
        const double te = (re[0] + re[1]) + (re[2] + re[3]);
        const float inv_s = 1.0f / (255.0f * (float)Bn * (float)Hn * (float)Wn);
        out[0] = (float)ts * inv_s;
        out[1] = (float)te * (inv_s / 3.0f);
    }
}

extern "C" void kernel_launch(void* const* d_in, const int* in_sizes, int n_in,
                              void* d_out, int out_size, void* d_ws, size_t ws_size,
                              hipStream_t stream) {
    const float* pred = (const float*)d_in[0];
    const float* tru  = (const float*)d_in[1];
    float* out = (float*)d_out;
    int2* ws = (int2*)d_ws;   // NBLK int2 partials = 8 KB

    csl_stream<<<NBLK, 256, 0, stream>>>(pred, tru, ws);
    reduce_kernel<<<1, 256, 0, stream>>>(ws, out);
}

// Round 14
// 125.139 us; speedup vs baseline: 1.0656x; 1.0656x over previous
//
#include <hip/hip_runtime.h>

// FINAL (champion, = R6/R11, bench 125.21/125.23 us reproducible):
// Fused ColorSobelLoss. 128x16 tile per 256-thread block, 2048 blocks.
// - u8 quantize + RGB2GRAY once per pixel; grays byte-packed (pred | true<<8)
//   in LDS (ushort), fully float4-coalesced global loads (12 in flight/thread).
// - Exact integer sobel (RNE(n/2) = h + (n&h&1)), |sp-st| fused.
// - threshold->gauss3x3->(blur>0) collapses to OR over 3x3 of 2-bit mask codes
//   (min nonzero blur = 255/16 -> rounds to 16 > 0): no float blur at all.
// - Edge loss needs only D=sum|up-ut|, Su=sum(up), St=sum(ut) per pixel,
//   packed 10+10+10 bits in one int (computed in f32 — exact, ints <= 765).
// - Per-block partials to d_ws (uncontended stores; the per-block atomicAdds
//   to one cache line cost ~17ns each serialized = 71us floor, measured R4->R6)
//   + tiny tree-reduce kernel.
// - launch_bounds(256,4): VGPR 44, no spills. (256,8) forces spills (R5),
//   (256,6) neutral (R7); tile 64x16 starves MLP (R3); 128x32 neutral (R9);
//   halo-first reorder spills (R10); barrier-free streaming benches worse
//   despite faster dispatch (R12/R13). All absmax 0.

typedef unsigned short us4 __attribute__((ext_vector_type(4)));

constexpr int Bn = 16, Hn = 512, Wn = 512;
constexpr int TX = 128, TY = 16;
constexpr int GR = TY + 4;    // 20 gray rows (halo 2)
constexpr int GCS = 136;      // gray row stride (ushort); used cols 2..133
constexpr int MR = TY + 2;    // 18 mask rows (halo 1)
constexpr int MCS = 136;      // mask stride (uchar); used cols 3..132
constexpr int NBLK = (Wn / TX) * (Hn / TY) * Bn;   // 2048

__device__ __forceinline__ float u8q(float v) {
    return floorf(fminf(fmaxf(v * 255.0f, 0.0f), 255.0f));
}
__device__ __forceinline__ int reflect101(int i, int n) {
    if (i < 0) return -i;
    if (i >= n) return 2 * n - 2 - i;
    return i;
}
__device__ __forceinline__ int gray1(float r, float g, float b) {
    return (int)rintf((0.299f * r + 0.587f * g) + 0.114f * b);
}
__device__ __forceinline__ int grayq(float r, float g, float b) {
    return gray1(u8q(r), u8q(g), u8q(b));
}
__device__ __forceinline__ int iabs(int v) { return v < 0 ? -v : v; }

__global__ __launch_bounds__(256, 4)
void csl_kernel(const float* __restrict__ pred, const float* __restrict__ tru,
                int2* __restrict__ ws) {
    const int b   = blockIdx.z;
    const int ty0 = blockIdx.y * TY;
    const int tx0 = blockIdx.x * TX;
    const int tid = threadIdx.x;

    __shared__ __align__(16) unsigned short gg[GR][GCS];
    __shared__ unsigned char mk[MR][MCS];
    __shared__ int wss[4], wse[4];

    const size_t chs = (size_t)Hn * Wn;
    const float* pb = pred + (size_t)b * 3 * chs;
    const float* tb = tru  + (size_t)b * 3 * chs;

    int Pk[8];  // per-pixel D | Su<<10 | St<<20

    // ---- Stage 1a: center 16x128, 8 px/thread, all 12 vec4 loads issued first ----
    {
        const int r0 = 2 + (tid >> 5), q0 = tid & 31;
        const int p1 = tid + 256;
        const int r1 = 2 + (p1 >> 5), q1 = p1 & 31;
        const size_t o0 = (size_t)(ty0 + r0 - 2) * Wn + tx0 + 4 * q0;
        const size_t o1 = (size_t)(ty0 + r1 - 2) * Wn + tx0 + 4 * q1;

        const float4 a0 = *(const float4*)(pb + o0);
        const float4 b0 = *(const float4*)(pb + chs + o0);
        const float4 c0 = *(const float4*)(pb + 2 * chs + o0);
        const float4 d0 = *(const float4*)(tb + o0);
        const float4 e0 = *(const float4*)(tb + chs + o0);
        const float4 f0 = *(const float4*)(tb + 2 * chs + o0);
        const float4 a1 = *(const float4*)(pb + o1);
        const float4 b1 = *(const float4*)(pb + chs + o1);
        const float4 c1 = *(const float4*)(pb + 2 * chs + o1);
        const float4 d1 = *(const float4*)(tb + o1);
        const float4 e1 = *(const float4*)(tb + chs + o1);
        const float4 f1 = *(const float4*)(tb + 2 * chs + o1);

        auto proc = [&](int r, int q, const float4& A, const float4& B,
                        const float4& C, const float4& D4, const float4& E,
                        const float4& F, int* pk) {
            const float* af = (const float*)&A; const float* bf = (const float*)&B;
            const float* cf = (const float*)&C; const float* df = (const float*)&D4;
            const float* ef = (const float*)&E; const float* ff = (const float*)&F;
            us4 gw;
            #pragma unroll
            for (int i = 0; i < 4; ++i) {
                const float pr = u8q(af[i]), pg = u8q(bf[i]), pl = u8q(cf[i]);
                const float tr_ = u8q(df[i]), tg = u8q(ef[i]), tl = u8q(ff[i]);
                const int gp = gray1(pr, pg, pl), gt = gray1(tr_, tg, tl);
                gw[i] = (unsigned short)(gp | (gt << 8));
                // exact in f32: operands are integers <= 765 < 2^24
                const float fD  = fabsf(pr - tr_) + fabsf(pg - tg) + fabsf(pl - tl);
                const float fSu = (pr + pg) + pl;
                const float fSt = (tr_ + tg) + tl;
                pk[i] = (int)fD | ((int)fSu << 10) | ((int)fSt << 20);
            }
            *(us4*)&gg[r][4 + 4 * q] = gw;
        };
        proc(r0, q0, a0, b0, c0, d0, e0, f0, Pk);
        proc(r1, q1, a1, b1, c1, d1, e1, f1, Pk + 4);
    }

    // ---- Stage 1b: halo rows 0,1,18,19 (vec4, gray only) ----
    if (tid < 128) {
        const int rh = tid >> 5;
        const int q = tid & 31;
        const int r = (rh < 2) ? rh : rh + 16;
        const int gy = reflect101(ty0 + r - 2, Hn);
        const size_t off = (size_t)gy * Wn + tx0 + 4 * q;
        const float4 A = *(const float4*)(pb + off);
        const float4 B = *(const float4*)(pb + chs + off);
        const float4 C = *(const float4*)(pb + 2 * chs + off);
        const float4 D4 = *(const float4*)(tb + off);
        const float4 E = *(const float4*)(tb + chs + off);
        const float4 F = *(const float4*)(tb + 2 * chs + off);
        const float* af = (const float*)&A; const float* bf = (const float*)&B;
        const float* cf = (const float*)&C; const float* df = (const float*)&D4;
        const float* ef = (const float*)&E; const float* ff = (const float*)&F;
        us4 gw;
        #pragma unroll
        for (int i = 0; i < 4; ++i) {
            const int gp = gray1(u8q(af[i]), u8q(bf[i]), u8q(cf[i]));
            const int gt = gray1(u8q(df[i]), u8q(ef[i]), u8q(ff[i]));
            gw[i] = (unsigned short)(gp | (gt << 8));
        }
        *(us4*)&gg[r][4 + 4 * q] = gw;
    } else if (tid < 168) {
        // ---- Stage 1c: halo cols (x_local -2,-1 -> cols 2,3; 128,129 -> 132,133) ----
        const int t = tid - 128;     // 0..39
        const int r = t >> 1;        // 0..19
        const int side = t & 1;
        const int gy = reflect101(ty0 + r - 2, Hn);
        const size_t rowo = (size_t)gy * Wn;
        if (side == 0) {
            if (tx0 > 0) {
                const size_t off = rowo + tx0 - 4;   // x_local -4..-1
                const float4 A = *(const float4*)(pb + off);
                const float4 B = *(const float4*)(pb + chs + off);
                const float4 C = *(const float4*)(pb + 2 * chs + off);
                const float4 D4 = *(const float4*)(tb + off);
                const float4 E = *(const float4*)(tb + chs + off);
                const float4 F = *(const float4*)(tb + 2 * chs + off);
                gg[r][2] = (unsigned short)(grayq(A.z, B.z, C.z) |
                                            (grayq(D4.z, E.z, F.z) << 8));
                gg[r][3] = (unsigned short)(grayq(A.w, B.w, C.w) |
                                            (grayq(D4.w, E.w, F.w) << 8));
            } else {
                const size_t o2 = rowo + 2, o1 = rowo + 1;   // reflect(-2)=2, reflect(-1)=1
                gg[r][2] = (unsigned short)(
                    grayq(pb[o2], pb[o2 + chs], pb[o2 + 2 * chs]) |
                    (grayq(tb[o2], tb[o2 + chs], tb[o2 + 2 * chs]) << 8));
                gg[r][3] = (unsigned short)(
                    grayq(pb[o1], pb[o1 + chs], pb[o1 + 2 * chs]) |
                    (grayq(tb[o1], tb[o1 + chs], tb[o1 + 2 * chs]) << 8));
            }
        } else {
            if (tx0 + TX < Wn) {
                const size_t off = rowo + tx0 + TX;  // x_local 128..131
                const float4 A = *(const float4*)(pb + off);
                const float4 B = *(const float4*)(pb + chs + off);
                const float4 C = *(const float4*)(pb + 2 * chs + off);
                const float4 D4 = *(const float4*)(tb + off);
                const float4 E = *(const float4*)(tb + chs + off);
                const float4 F = *(const float4*)(tb + 2 * chs + off);
                gg[r][132] = (unsigned short)(grayq(A.x, B.x, C.x) |
                                              (grayq(D4.x, E.x, F.x) << 8));
                gg[r][133] = (unsigned short)(grayq(A.y, B.y, C.y) |
                                              (grayq(D4.y, E.y, F.y) << 8));
            } else {
                const size_t oa = rowo + 510, ob = rowo + 509; // reflect(512),(513)
                gg[r][132] = (unsigned short)(
                    grayq(pb[oa], pb[oa + chs], pb[oa + 2 * chs]) |
                    (grayq(tb[oa], tb[oa + chs], tb[oa + 2 * chs]) << 8));
                gg[r][133] = (unsigned short)(
                    grayq(pb[ob], pb[ob + chs], pb[ob + 2 * chs]) |
                    (grayq(tb[ob], tb[ob + chs], tb[ob + 2 * chs]) << 8));
            }
        }
    }
    __syncthreads();

    // ---- Stage 2: int sobel on packed bytes, |sp-st| loss, 2-bit mask codes ----
    int accS = 0;
    auto sob4 = [&](int r, int q, bool center) {
        const int cb = 4 + 4 * q;
        const us4 U = *(const us4*)&gg[r][cb];
        const us4 M = *(const us4*)&gg[r + 1][cb];
        const us4 D = *(const us4*)&gg[r + 2][cb];
        const int ml = gg[r + 1][cb - 1];
        const int mr = gg[r + 1][cb + 4];
        const int m[6] = {ml, M.x, M.y, M.z, M.w, mr};
        const int u[4] = {U.x, U.y, U.z, U.w};
        const int d[4] = {D.x, D.y, D.z, D.w};
        unsigned cw = 0;
        #pragma unroll
        for (int i = 0; i < 4; ++i) {
            const int dxp = (m[i + 2] & 255) - (m[i] & 255);
            const int dyp = (d[i] & 255) - (u[i] & 255);
            const int dxt = (m[i + 2] >> 8) - (m[i] >> 8);
            const int dyt = (d[i] >> 8) - (u[i] >> 8);
            const int np = iabs(dxp) + iabs(dyp);
            const int nt = iabs(dxt) + iabs(dyt);
            const int hp = np >> 1, ht = nt >> 1;
            const int sp = hp + (np & hp & 1);   // RNE(np/2)
            const int st = ht + (nt & ht & 1);
            if (center) accS += iabs(sp - st);
            cw |= ((sp > 10 ? 1u : 0u) | (st > 10 ? 2u : 0u)) << (8 * i);
        }
        *(unsigned*)&mk[r][cb] = cw;
    };
    {
        const int r = tid >> 5, q = tid & 31;       // rows 0..7
        sob4(r, q, r >= 1);
    }
    {
        const int p1 = tid + 256;                    // rows 8..15, all center
        sob4(p1 >> 5, p1 & 31, true);
    }
    if (tid < 64) {
        const int p2 = tid + 512;                    // rows 16,17
        const int r = p2 >> 5;
        sob4(r, p2 & 31, r == 16);
    } else if (tid < 100) {
        // halo mask cols 3 (x=-1) and 132 (x=128)
        const int t = tid - 64;
        const int r = t >> 1;
        const int gc = (t & 1) ? 132 : 3;
        const int l = gg[r + 1][gc - 1], rr = gg[r + 1][gc + 1];
        const int uu = gg[r][gc], dd = gg[r + 2][gc];
        const int np = iabs((rr & 255) - (l & 255)) + iabs((dd & 255) - (uu & 255));
        const int nt = iabs((rr >> 8) - (l >> 8)) + iabs((dd >> 8) - (uu >> 8));
        const int hp = np >> 1, ht = nt >> 1;
        const int sp = hp + (np & hp & 1);
        const int st = ht + (nt & ht & 1);
        mk[r][gc] = (unsigned char)((sp > 10 ? 1u : 0u) | (st > 10 ? 2u : 0u));
    }
    __syncthreads();

    // ---- Stage 3: keep = OR over 3x3 codes; edge loss in int ----
    int accE = 0;
    #pragma unroll
    for (int j = 0; j < 2; ++j) {
        const int pos = tid + 256 * j;
        const int py = pos >> 5;       // 0..15, matches stage-1a slot j
        const int q = pos & 31;
        const int cb = 4 + 4 * q;
        unsigned Lo = 0, Co = 0, Ro = 0;
        #pragma unroll
        for (int d = 0; d < 3; ++d) {
            Lo |= *(const unsigned*)&mk[py + d][cb - 4];
            Co |= *(const unsigned*)&mk[py + d][cb];
            Ro |= *(const unsigned*)&mk[py + d][cb + 4];
        }
        unsigned long long w = (unsigned long long)(Lo >> 24) |
                               ((unsigned long long)Co << 8) |
                               ((unsigned long long)(Ro & 0xFFu) << 40);
        unsigned long long t3 = w | (w >> 8) | (w >> 16);
        const int* Pp = &Pk[4 * j];
        #pragma unroll
        for (int i = 0; i < 4; ++i) {
            const unsigned code = (unsigned)(t3 >> (8 * i)) & 3u;
            const int D = Pp[i] & 1023;
            const int Su = (Pp[i] >> 10) & 1023;
            const int St = Pp[i] >> 20;
            const int s1 = (code & 2u) ? D : Su;
            const int s0 = (code & 2u) ? St : 0;
            accE += (code & 1u) ? s1 : s0;
        }
    }

    // ---- Block reduction -> uncontended partial-sum store ----
    #pragma unroll
    for (int off = 32; off > 0; off >>= 1) {
        accS += __shfl_down(accS, off, 64);
        accE += __shfl_down(accE, off, 64);
    }
    const int wave = tid >> 6, lane = tid & 63;
    if (lane == 0) { wss[wave] = accS; wse[wave] = accE; }
    __syncthreads();
    if (tid == 0) {
        const int ts = (wss[0] + wss[1]) + (wss[2] + wss[3]);
        const int te = (wse[0] + wse[1]) + (wse[2] + wse[3]);
        const int bid = (blockIdx.z * gridDim.y + blockIdx.y) * gridDim.x + blockIdx.x;
        ws[bid] = make_int2(ts, te);
    }
}

__global__ __launch_bounds__(256)
void reduce_kernel(const int2* __restrict__ ws, float* __restrict__ out) {
    const int tid = threadIdx.x;
    int s = 0, e = 0;
    for (int i = tid; i < NBLK; i += 256) {
        const int2 v = ws[i];
        s += v.x; e += v.y;
    }
    double ds = (double)s, de = (double)e;
    #pragma unroll
    for (int off = 32; off > 0; off >>= 1) {
        ds += __shfl_down(ds, off, 64);
        de += __shfl_down(de, off, 64);
    }
    __shared__ double rs[4], re[4];
    const int wave = tid >> 6, lane = tid & 63;
    if (lane == 0) { rs[wave] = ds; re[wave] = de; }
    __syncthreads();
    if (tid == 0) {
        const double ts = (rs[0] + rs[1]) + (rs[2] + rs[3]);
        const double te = (re[0] + re[1]) + (re[2] + re[3]);
        const float inv_s = 1.0f / (255.0f * (float)Bn * (float)Hn * (float)Wn);
        out[0] = (float)ts * inv_s;
        out[1] = (float)te * (inv_s / 3.0f);
    }
}

extern "C" void kernel_launch(void* const* d_in, const int* in_sizes, int n_in,
                              void* d_out, int out_size, void* d_ws, size_t ws_size,
                              hipStream_t stream) {
    const float* pred = (const float*)d_in[0];
    const float* tru  = (const float*)d_in[1];
    float* out = (float*)d_out;
    int2* ws = (int2*)d_ws;   // NBLK int2 partials = 16 KB

    dim3 grid(Wn / TX, Hn / TY, Bn);  // 4 x 32 x 16 = 2048 blocks
    csl_kernel<<<grid, 256, 0, stream>>>(pred, tru, ws);
    reduce_kernel<<<1, 256, 0, stream>>>(ws, out);
}